// Round 5
// baseline (1507.160 us; speedup 1.0000x reference)
//
#include <hip/hip_runtime.h>
#include <hip/hip_bf16.h>
#include <stdint.h>

// Problem sizes (fixed by the reference)
#define IN_F  4096
#define OUT_F 4096
#define NROWS 16384
#define NT    (IN_F / 64)   // 64 K-tiles of BK=64

typedef unsigned short u16;
typedef unsigned long long u64;
typedef __bf16 bf16x8 __attribute__((ext_vector_type(8)));
typedef float  f32x4  __attribute__((ext_vector_type(4)));
typedef u16    u16x8  __attribute__((ext_vector_type(8)));

#define BAR()   asm volatile("s_barrier" ::: "memory")
#define LGKM0() asm volatile("s_waitcnt lgkmcnt(0)" ::: "memory")
#define VM4()   asm volatile("s_waitcnt vmcnt(4)" ::: "memory")
#define VM0()   asm volatile("s_waitcnt vmcnt(0)" ::: "memory")

// fp32 -> bf16, round-to-nearest-even (finite inputs only)
__device__ __forceinline__ u16 f2bf(float x) {
    union { float f; uint32_t u; } c; c.f = x;
    uint32_t u = c.u;
    return (u16)((u + 0x7FFFu + ((u >> 16) & 1u)) >> 16);
}

// async global->LDS, 16B per lane. LDS dest = wave-uniform base + lane*16.
__device__ __forceinline__ void gload_lds16(const void* g, void* l) {
    __builtin_amdgcn_global_load_lds(
        (const __attribute__((address_space(1))) void*)g,
        (__attribute__((address_space(3))) void*)l, 16, 0, 0);
}

__device__ __forceinline__ u16 sgn_bf16(float v) {
    return v > 0.f ? 0x3F80 : (v < 0.f ? 0xBF80 : 0);
}

// --- Prep 1 (fast path): per-row alpha = mean(|W|) AND bit-packed signs.
// Wbits[row][kword] bit b = (W[row][kword*64+b] > 0). Whole B = 2 MB ->
// L2-resident in every XCD (r4 verified: FETCH 1.16GB -> 102MB).
__global__ void prep_wbits_kernel(const float* __restrict__ W,
                                  float* __restrict__ alpha,
                                  u64* __restrict__ Wbits) {
    const int row = blockIdx.x;                       // 0..OUT_F-1
    const int wave = threadIdx.x >> 6, lane = threadIdx.x & 63;
    const float* wr = W + (size_t)row * IN_F;
    float s = 0.f;
#pragma unroll 4
    for (int it = 0; it < 16; ++it) {
        const int kword = it * 4 + wave;              // 64 words per row
        float v = __builtin_nontemporal_load(wr + kword * 64 + lane);
        s += fabsf(v);
        u64 m = __ballot(v > 0.f);                    // 64-bit wave mask
        if (lane == 0) Wbits[(size_t)row * 64 + kword] = m;
    }
    for (int off = 32; off > 0; off >>= 1) s += __shfl_down(s, off);
    __shared__ float red[4];
    if (lane == 0) red[wave] = s;
    __syncthreads();
    if (threadIdx.x == 0)
        alpha[row] = (red[0] + red[1] + red[2] + red[3]) * (1.0f / IN_F);
}

// --- Prep 2: x fp32 -> bf16 (RNE), chunk-swizzled for T2 (c8 ^= row&7) ---
__global__ void convx_kernel(const float* __restrict__ X, u16* __restrict__ O,
                             int swz) {
    const size_t idx = (size_t)blockIdx.x * 256 + threadIdx.x; // 16B out chunk
    const int row = (int)(idx >> 9);                 // 512 chunks per row
    const int q = (int)idx & 511;
    const int g = q >> 3, c8 = q & 7;
    const int c8s = swz ? (c8 ^ (row & 7)) : c8;
    const f32x4* src = reinterpret_cast<const f32x4*>(
        X + (size_t)row * IN_F + g * 64 + c8s * 8);
    f32x4 a = __builtin_nontemporal_load(src);
    f32x4 b = __builtin_nontemporal_load(src + 1);
    u16x8 r;
    r[0] = f2bf(a[0]); r[1] = f2bf(a[1]); r[2] = f2bf(a[2]); r[3] = f2bf(a[3]);
    r[4] = f2bf(b[0]); r[5] = f2bf(b[1]); r[6] = f2bf(b[2]); r[7] = f2bf(b[3]);
    reinterpret_cast<u16x8*>(O)[idx] = r;
}

// ============================================================================
// 256x256 GEMM, bit-B edition, round 5: PIPELINED B-expansion.
// r4 showed the bit->bf16 expansion (~220 VALU/lane/tile) sat in phi0's
// critical section (VALUBusy 16->42%, MfmaUtil 41->32.5%, dur +128us).
// Change: loadB two tiles ahead; expand B(t+1) during tile t, placed AFTER
// the phi1/phi2 MFMA clusters (2 frags each) so the VALU retires under the
// matrix pipe; asm fake-uses pin the placement. Double-buffered frag regs
// (bfrA/bfrB) via 2-tile-unrolled loop (static indexing, no scratch).
// vmcnt ledger (re-derived): S(t) = {A(t+1)x4}. Tile t issues B(t+2)x4 @phi0,
// A(t+2)x4 @phi1/2 -> 12 outstanding -> VM4 drains A(t+1)+B(t+2), leaves
// A(t+2)x4 = S(t+1). bits(t+1) drained at t-1's boundary -> expandable all
// of tile t. Tail: t>=62 uses VM0 (A(63) must complete; VM4 would no-op).
// Prologue: B(0),B(1),A(0),A(1) issued (16) -> VM4 leaves A(1)x4 ✓.
// ============================================================================
__global__ __launch_bounds__(512, 2) void gemm8_kernel(
    const u16* __restrict__ Xbf, const u64* __restrict__ Wbits,
    const float* __restrict__ alpha, const float* __restrict__ bias,
    float* __restrict__ Y) {
    __shared__ u16 lds_[49152];   // 96 KiB: 3 A-tile buffers of 16384 u16

    const int tid  = threadIdx.x;
    const int lane = tid & 63, wave = tid >> 6;
    const int wm = wave >> 2, wn = wave & 3;      // 2(M) x 4(N) waves
    const int lrow = lane & 15;

    const int wg = blockIdx.x;
    const int i  = wg >> 3;                       // 0..127 within XCD
    const int m0 = (((wg & 7) << 3) | (i >> 4)) << 8;   // xcd*8 + m_local
    const int n0 = (i & 15) << 8;

    // T2 swizzled ds_read k-offsets (u16 units)
    const int q0 = ((lane >> 4) << 3) ^ ((lrow & 7) << 3);
    const int q1 = q0 ^ 32;
    const int sh = (lane >> 4) << 3;              // bit offset for kk=0 byte

    f32x4 acc[8][4];
#pragma unroll
    for (int a = 0; a < 8; ++a)
#pragma unroll
        for (int b = 0; b < 4; ++b) acc[a][b] = (f32x4){0.f, 0.f, 0.f, 0.f};

    // stage one 128-row half of A K-tile th into buf (2 gload_lds16 / thread)
    auto stageA = [&](int th, int half, u16* buf) {
        if (th >= NT) return;
#pragma unroll
        for (int t2 = 0; t2 < 2; ++t2) {
            const int c = half * 1024 + t2 * 512 + tid;   // 16B chunk idx
            const int row = c >> 3, c8 = c & 7;
            gload_lds16(Xbf + (size_t)(m0 + row) * IN_F + th * 64 + c8 * 8,
                        buf + c * 8);
        }
    };

    u64 wA[4], wB[4];
    auto loadB = [&](int th, u64* w) {
        if (th >= NT) return;
#pragma unroll
        for (int nf = 0; nf < 4; ++nf)
            w[nf] = Wbits[(size_t)(n0 + wn * 64 + nf * 16 + lrow) * 64 + th];
    };

    bf16x8 bfrA[4][2], bfrB[4][2];

    // expand one frag-column nf from bit-source into dst; fake-use pins it.
    // u32 e: low bf16 <- bit(2e), high bf16 <- bit(2e+1); sign set when bit=0:
    // r = 0x3F803F80 | ((~b>>2e &1)<<15) | ((~b>>2e &2)<<30)
    auto expand1 = [&](const u64* src, bf16x8 (*dst)[2], int nf) {
        u64 t64 = src[nf] >> sh;
        unsigned nb0 = ~(unsigned)t64;            // kk=0 bits at [7:0]
        unsigned nb1 = ~(unsigned)(t64 >> 32);    // kk=1 bits at [7:0]
        union { unsigned u[4]; bf16x8 v; } r0, r1;
#pragma unroll
        for (int e = 0; e < 4; ++e) {
            unsigned s0 = nb0 >> (2 * e), s1 = nb1 >> (2 * e);
            r0.u[e] = 0x3F803F80u | ((s0 & 1u) << 15) | ((s0 & 2u) << 30);
            r1.u[e] = 0x3F803F80u | ((s1 & 1u) << 15) | ((s1 & 2u) << 30);
        }
        dst[nf][0] = r0.v; dst[nf][1] = r1.v;
        asm volatile("" :: "v"(dst[nf][0]), "v"(dst[nf][1]));
    };

    u16* b0 = lds_;
    u16* b1 = lds_ + 16384;
    u16* b2 = lds_ + 32768;

    // prologue: B(0),B(1),A(0),A(1) -> 16 outstanding -> VM4 leaves A(1)x4.
    loadB(0, wA); loadB(1, wB);
    stageA(0, 0, b0); stageA(0, 1, b0);
    stageA(1, 0, b1); stageA(1, 1, b1);
    VM4(); BAR();
    expand1(wA, bfrA, 0); expand1(wA, bfrA, 1);
    expand1(wA, bfrA, 2); expand1(wA, bfrA, 3);

    u16* br = b0; u16* bn = b1; u16* bs = b2;

    // one K-tile: BC = expanded B(t) [consumed], BN <- expand from WSRC
    // (= bits(t+1), drained), WDST <- loadB(t+2) bits.
    auto tile_body = [&](int t, bf16x8 (&BC)[4][2], bf16x8 (&BN)[4][2],
                         const u64 (&WSRC)[4], u64 (&WDST)[4], bool last2) {
        const u16* Ab = br + wm * 8192 + lrow * 64;
        bf16x8 a0[4][2], a1[4][2];

        // --- phi0: ds_read a0; issue B(t+2); MFMA mh0 x np0 ---
#pragma unroll
        for (int mm = 0; mm < 4; ++mm) {
            a0[mm][0] = *reinterpret_cast<const bf16x8*>(Ab + mm * 1024 + q0);
            a0[mm][1] = *reinterpret_cast<const bf16x8*>(Ab + mm * 1024 + q1);
        }
        loadB(t + 2, WDST);
        BAR(); LGKM0();
        __builtin_amdgcn_s_setprio(1);
#pragma unroll
        for (int mm = 0; mm < 4; ++mm)
#pragma unroll
            for (int nn = 0; nn < 2; ++nn) {
                acc[mm][nn] = __builtin_amdgcn_mfma_f32_16x16x32_bf16(a0[mm][0], BC[nn][0], acc[mm][nn], 0, 0, 0);
                acc[mm][nn] = __builtin_amdgcn_mfma_f32_16x16x32_bf16(a0[mm][1], BC[nn][1], acc[mm][nn], 0, 0, 0);
            }
        __builtin_amdgcn_s_setprio(0);
        BAR();

        // --- phi1: ds_read a1; stage A(t+2) lo; MFMA mh0 x np1; expand nf0,1 ---
#pragma unroll
        for (int mm = 0; mm < 4; ++mm) {
            a1[mm][0] = *reinterpret_cast<const bf16x8*>(Ab + (4 + mm) * 1024 + q0);
            a1[mm][1] = *reinterpret_cast<const bf16x8*>(Ab + (4 + mm) * 1024 + q1);
        }
        stageA(t + 2, 0, bs);
        BAR();
        __builtin_amdgcn_s_setprio(1);
#pragma unroll
        for (int mm = 0; mm < 4; ++mm)
#pragma unroll
            for (int nn = 0; nn < 2; ++nn) {
                acc[mm][2 + nn] = __builtin_amdgcn_mfma_f32_16x16x32_bf16(a0[mm][0], BC[2 + nn][0], acc[mm][2 + nn], 0, 0, 0);
                acc[mm][2 + nn] = __builtin_amdgcn_mfma_f32_16x16x32_bf16(a0[mm][1], BC[2 + nn][1], acc[mm][2 + nn], 0, 0, 0);
            }
        __builtin_amdgcn_s_setprio(0);
        expand1(WSRC, BN, 0); expand1(WSRC, BN, 1);   // hides under phi1 MFMAs
        BAR();

        // --- phi2: stage A(t+2) hi; drain a1; MFMA mh1 x np0; expand nf2,3 ---
        stageA(t + 2, 1, bs);
        BAR(); LGKM0();
        __builtin_amdgcn_s_setprio(1);
#pragma unroll
        for (int mm = 0; mm < 4; ++mm)
#pragma unroll
            for (int nn = 0; nn < 2; ++nn) {
                acc[4 + mm][nn] = __builtin_amdgcn_mfma_f32_16x16x32_bf16(a1[mm][0], BC[nn][0], acc[4 + mm][nn], 0, 0, 0);
                acc[4 + mm][nn] = __builtin_amdgcn_mfma_f32_16x16x32_bf16(a1[mm][1], BC[nn][1], acc[4 + mm][nn], 0, 0, 0);
            }
        __builtin_amdgcn_s_setprio(0);
        expand1(WSRC, BN, 2); expand1(WSRC, BN, 3);   // hides under phi2 MFMAs
        BAR();

        // --- phi3: MFMA mh1 x np1; boundary vmcnt ---
        __builtin_amdgcn_s_setprio(1);
#pragma unroll
        for (int mm = 0; mm < 4; ++mm)
#pragma unroll
            for (int nn = 0; nn < 2; ++nn) {
                acc[4 + mm][2 + nn] = __builtin_amdgcn_mfma_f32_16x16x32_bf16(a1[mm][0], BC[2 + nn][0], acc[4 + mm][2 + nn], 0, 0, 0);
                acc[4 + mm][2 + nn] = __builtin_amdgcn_mfma_f32_16x16x32_bf16(a1[mm][1], BC[2 + nn][1], acc[4 + mm][2 + nn], 0, 0, 0);
            }
        __builtin_amdgcn_s_setprio(0);
        if (last2) { VM0(); } else { VM4(); }
        BAR();

        // rotate LDS buffers (runtime pointers -> no scratch)
        u16* tp = br; br = bn; bn = bs; bs = tp;
    };

    for (int it = 0; it < 32; ++it) {
        const bool l2 = (it == 31);
        tile_body(2 * it,     bfrA, bfrB, wB, wA, l2);
        tile_body(2 * it + 1, bfrB, bfrA, wA, wB, l2);
    }

    // epilogue: y = acc*alpha[col] + bias[col]; C/D: col=lane&15, row=(lane>>4)*4+r
#pragma unroll
    for (int nf = 0; nf < 4; ++nf) {
        const int col = n0 + wn * 64 + nf * 16 + lrow;
        const float al = alpha[col], bi = bias[col];
#pragma unroll
        for (int mf = 0; mf < 8; ++mf) {
            const int rbase = m0 + wm * 128 + mf * 16 + ((lane >> 4) << 2);
#pragma unroll
            for (int r = 0; r < 4; ++r)
                __builtin_nontemporal_store(acc[mf][nf][r] * al + bi,
                    &Y[(size_t)(rbase + r) * OUT_F + col]);
        }
    }
}

// ============================================================================
// Fallback (small workspace): round-1 128x128 kernel, A reg-staged from fp32,
// bf16 Wsign unswizzled. Verified correct in round 1.
// ============================================================================
__global__ void prep_w_kernel(const float* __restrict__ W,
                              float* __restrict__ alpha,
                              u16* __restrict__ S) {
    const int row = blockIdx.x;
    const float* wr = W + (size_t)row * IN_F;
    float s = 0.f;
    for (int c = threadIdx.x; c < 512; c += 256) {
        const f32x4* src = reinterpret_cast<const f32x4*>(wr + c * 8);
        f32x4 v0 = __builtin_nontemporal_load(src);
        f32x4 v1 = __builtin_nontemporal_load(src + 1);
        s += fabsf(v0[0]) + fabsf(v0[1]) + fabsf(v0[2]) + fabsf(v0[3])
           + fabsf(v1[0]) + fabsf(v1[1]) + fabsf(v1[2]) + fabsf(v1[3]);
        u16x8 r;
        r[0] = sgn_bf16(v0[0]); r[1] = sgn_bf16(v0[1]);
        r[2] = sgn_bf16(v0[2]); r[3] = sgn_bf16(v0[3]);
        r[4] = sgn_bf16(v1[0]); r[5] = sgn_bf16(v1[1]);
        r[6] = sgn_bf16(v1[2]); r[7] = sgn_bf16(v1[3]);
        *reinterpret_cast<u16x8*>(S + (size_t)row * IN_F + c * 8) = r;
    }
    for (int off = 32; off > 0; off >>= 1) s += __shfl_down(s, off);
    __shared__ float red[4];
    const int wave = threadIdx.x >> 6, lane = threadIdx.x & 63;
    if (lane == 0) red[wave] = s;
    __syncthreads();
    if (threadIdx.x == 0)
        alpha[row] = (red[0] + red[1] + red[2] + red[3]) * (1.0f / IN_F);
}

__global__ __launch_bounds__(256) void gemm_fallback(
    const float* __restrict__ X, const u16* __restrict__ Wsign,
    const float* __restrict__ alpha, const float* __restrict__ bias,
    float* __restrict__ Y) {
    __shared__ u16 Alds[128 * 64];
    __shared__ u16 Blds[128 * 64];

    const int tid = threadIdx.x;
    const int n0 = blockIdx.x * 128;
    const int m0 = blockIdx.y * 128;
    const int wave = tid >> 6, lane = tid & 63;
    const int wm = wave >> 1, wn = wave & 1;
    const int lrow = lane & 15;
    const int lk8 = (lane >> 4) * 8;

    f32x4 acc[4][4];
#pragma unroll
    for (int a = 0; a < 4; ++a)
#pragma unroll
        for (int b = 0; b < 4; ++b) acc[a][b] = (f32x4){0.f, 0.f, 0.f, 0.f};

    for (int kt = 0; kt < IN_F; kt += 64) {
#pragma unroll
        for (int j = 0; j < 4; ++j) {
            const int idx = j * 256 + tid;
            const int row = idx >> 3, c8 = idx & 7;
            gload_lds16(Wsign + (size_t)(n0 + row) * IN_F + kt + c8 * 8,
                        &Blds[idx * 8]);
        }
#pragma unroll
        for (int j = 0; j < 4; ++j) {
            const int idx = j * 256 + tid;
            const int row = idx >> 3, c8 = idx & 7;
            const float* src = X + (size_t)(m0 + row) * IN_F + kt + c8 * 8;
            float4 v0 = *reinterpret_cast<const float4*>(src);
            float4 v1 = *reinterpret_cast<const float4*>(src + 4);
            u16x8 r;
            r[0] = f2bf(v0.x); r[1] = f2bf(v0.y); r[2] = f2bf(v0.z); r[3] = f2bf(v0.w);
            r[4] = f2bf(v1.x); r[5] = f2bf(v1.y); r[6] = f2bf(v1.z); r[7] = f2bf(v1.w);
            *reinterpret_cast<u16x8*>(&Alds[idx * 8]) = r;
        }
        __syncthreads();
#pragma unroll
        for (int kk = 0; kk < 2; ++kk) {
            bf16x8 af[4], bfv[4];
#pragma unroll
            for (int mf = 0; mf < 4; ++mf)
                af[mf] = *reinterpret_cast<const bf16x8*>(
                    &Alds[(wm * 64 + mf * 16 + lrow) * 64 + kk * 32 + lk8]);
#pragma unroll
            for (int nf = 0; nf < 4; ++nf)
                bfv[nf] = *reinterpret_cast<const bf16x8*>(
                    &Blds[(wn * 64 + nf * 16 + lrow) * 64 + kk * 32 + lk8]);
#pragma unroll
            for (int mf = 0; mf < 4; ++mf)
#pragma unroll
                for (int nf = 0; nf < 4; ++nf)
                    acc[mf][nf] = __builtin_amdgcn_mfma_f32_16x16x32_bf16(
                        af[mf], bfv[nf], acc[mf][nf], 0, 0, 0);
        }
        __syncthreads();
    }
#pragma unroll
    for (int nf = 0; nf < 4; ++nf) {
        const int col = n0 + wn * 64 + nf * 16 + lrow;
        const float al = alpha[col], bi = bias[col];
#pragma unroll
        for (int mf = 0; mf < 4; ++mf) {
            const int rbase = m0 + wm * 64 + mf * 16 + (lane >> 4) * 4;
#pragma unroll
            for (int r = 0; r < 4; ++r)
                __builtin_nontemporal_store(acc[mf][nf][r] * al + bi,
                    &Y[(size_t)(rbase + r) * OUT_F + col]);
        }
    }
}

extern "C" void kernel_launch(void* const* d_in, const int* in_sizes, int n_in,
                              void* d_out, int out_size, void* d_ws, size_t ws_size,
                              hipStream_t stream) {
    const float* X    = (const float*)d_in[0];
    const float* W    = (const float*)d_in[1];
    const float* bias = (const float*)d_in[2];
    float* Y = (float*)d_out;

    char* ws = (char*)d_ws;
    float* alpha = (float*)ws;                               // 16 KB
    const size_t WBITS_OFF = 16384;
    const size_t XBF_OFF   = WBITS_OFF + (size_t)OUT_F * (IN_F / 8); // +2 MB
    const size_t need_fast = XBF_OFF + (size_t)NROWS * IN_F * 2;     // +128 MB
    const size_t need_safe = 16384 + (size_t)OUT_F * IN_F * 2;       // 32 MB path

    if (ws_size >= need_fast) {
        u64* Wbits = (u64*)(ws + WBITS_OFF);
        u16* Xbf   = (u16*)(ws + XBF_OFF);
        prep_wbits_kernel<<<OUT_F, 256, 0, stream>>>(W, alpha, Wbits);
        convx_kernel<<<(size_t)NROWS * IN_F / 8 / 256, 256, 0, stream>>>(X, Xbf, 1);
        gemm8_kernel<<<dim3(1024), 512, 0, stream>>>(Xbf, Wbits, alpha, bias, Y);
    } else {
        u16* Wsign = (u16*)(ws + 16384);
        prep_w_kernel<<<OUT_F, 256, 0, stream>>>(W, alpha, Wsign);
        dim3 grid(OUT_F / 128, NROWS / 128);
        gemm_fallback<<<grid, 256, 0, stream>>>(X, Wsign, alpha, bias, Y);
    }
}

// Round 6
// 585.239 us; speedup vs baseline: 2.5753x; 2.5753x over previous
//
#include <hip/hip_runtime.h>
#include <hip/hip_bf16.h>
#include <stdint.h>

// Problem sizes (fixed by the reference)
#define IN_F  4096
#define OUT_F 4096
#define NROWS 16384
#define NT    (IN_F / 64)   // 64 K-tiles of BK=64

typedef unsigned short u16;
typedef unsigned int u32;
typedef unsigned long long u64;
typedef __bf16 bf16x8 __attribute__((ext_vector_type(8)));
typedef float  f32x4  __attribute__((ext_vector_type(4)));
typedef u16    u16x8  __attribute__((ext_vector_type(8)));

#define BAR()   asm volatile("s_barrier" ::: "memory")
#define LGKM0() asm volatile("s_waitcnt lgkmcnt(0)" ::: "memory")
#define VM0()   asm volatile("s_waitcnt vmcnt(0)" ::: "memory")

// fp32 -> bf16, round-to-nearest-even (finite inputs only)
__device__ __forceinline__ u16 f2bf(float x) {
    union { float f; uint32_t u; } c; c.f = x;
    uint32_t u = c.u;
    return (u16)((u + 0x7FFFu + ((u >> 16) & 1u)) >> 16);
}

// async global->LDS, 16B per lane. LDS dest = wave-uniform base + lane*16.
__device__ __forceinline__ void gload_lds16(const void* g, void* l) {
    __builtin_amdgcn_global_load_lds(
        (const __attribute__((address_space(1))) void*)g,
        (__attribute__((address_space(3))) void*)l, 16, 0, 0);
}

__device__ __forceinline__ u16 sgn_bf16(float v) {
    return v > 0.f ? 0x3F80 : (v < 0.f ? 0xBF80 : 0);
}

// --- Prep 1 (fast path): per-row alpha = mean(|W|) AND bit-packed signs,
// TRANSPOSED layout: Wbits[kword][row], so one K-tile's bits for 256 rows
// are a contiguous 2KB burst (fully coalesced per-WG load in the GEMM).
// Whole bitmap = 2 MB -> L2-resident in every XCD (r4: FETCH 1.16GB->102MB).
__global__ void prep_wbits_kernel(const float* __restrict__ W,
                                  float* __restrict__ alpha,
                                  u64* __restrict__ Wbits) {
    const int row = blockIdx.x;                       // 0..OUT_F-1
    const int wave = threadIdx.x >> 6, lane = threadIdx.x & 63;
    const float* wr = W + (size_t)row * IN_F;
    float s = 0.f;
#pragma unroll 4
    for (int it = 0; it < 16; ++it) {
        const int kword = it * 4 + wave;              // 64 words per row
        float v = __builtin_nontemporal_load(wr + kword * 64 + lane);
        s += fabsf(v);
        u64 m = __ballot(v > 0.f);                    // 64-bit wave mask
        if (lane == 0) Wbits[(size_t)kword * OUT_F + row] = m;   // transposed
    }
    for (int off = 32; off > 0; off >>= 1) s += __shfl_down(s, off);
    __shared__ float red[4];
    if (lane == 0) red[wave] = s;
    __syncthreads();
    if (threadIdx.x == 0)
        alpha[row] = (red[0] + red[1] + red[2] + red[3]) * (1.0f / IN_F);
}

// --- Prep 2: x fp32 -> bf16 (RNE), chunk-swizzled for T2 (c8 ^= row&7) ---
__global__ void convx_kernel(const float* __restrict__ X, u16* __restrict__ O,
                             int swz) {
    const size_t idx = (size_t)blockIdx.x * 256 + threadIdx.x; // 16B out chunk
    const int row = (int)(idx >> 9);                 // 512 chunks per row
    const int q = (int)idx & 511;
    const int g = q >> 3, c8 = q & 7;
    const int c8s = swz ? (c8 ^ (row & 7)) : c8;
    const f32x4* src = reinterpret_cast<const f32x4*>(
        X + (size_t)row * IN_F + g * 64 + c8s * 8);
    f32x4 a = __builtin_nontemporal_load(src);
    f32x4 b = __builtin_nontemporal_load(src + 1);
    u16x8 r;
    r[0] = f2bf(a[0]); r[1] = f2bf(a[1]); r[2] = f2bf(a[2]); r[3] = f2bf(a[3]);
    r[4] = f2bf(b[0]); r[5] = f2bf(b[1]); r[6] = f2bf(b[2]); r[7] = f2bf(b[3]);
    reinterpret_cast<u16x8*>(O)[idx] = r;
}

// ============================================================================
// 256x256 GEMM, bit-B round 6: WG-COOPERATIVE LDS EXPANSION.
// r5 post-mortem: per-lane double-buffered B-frag registers blew the full
// 256-reg/wave budget (acc 128 AGPR + 128 VGPR) -> scratch spill (WRITE 3GB).
// Fix: expand bits in LDS instead. Per tile, B bits = 2KB; each of 512
// threads expands ONE u32 -> 32 bf16 (4 ds_write_b128, ~50 VALU), placed
// AFTER the phi1/phi2 MFMA clusters (independent of acc -> issues under the
// matrix pipe; barrier-pinned). Per-lane extra state: 2 scalar u32 -> zero
// register pressure; a0/a1/bfr layout identical to the proven r2-r4 kernel.
// LDS: A dbuf 2x32KB + B dbuf 2x32KB = 128KB (proven size).
// Partition (r4, verified FETCH 102MB): xcd=wg&7 owns 8 m-tiles x 16 n-tiles;
// n fast -> co-resident 2m x 16n share A-slabs in L2; bits 2MB L2-resident.
// vmcnt ledger: per tile issue bits(t+2)[phi0], A(t+1)lo x2 [phi1],
// A(t+1)hi x2 [phi2] = 5 outstanding; boundary = LGKM0 (expansion ds_writes
// visible) + VM0 (all 5 needed by t+1). Invariant entering t: all vm
// complete, bits_cur = bits(t+1) in reg, Alds[t&1]=A(t), Blds[t&1]=B(t).
// ============================================================================
__global__ __launch_bounds__(512, 2) void gemm8_kernel(
    const u16* __restrict__ Xbf, const u64* __restrict__ Wbits,
    const float* __restrict__ alpha, const float* __restrict__ bias,
    float* __restrict__ Y) {
    __shared__ u16 Alds[2][16384];   // [2][256 rows][64 k]
    __shared__ u16 Blds[2][16384];   // [2][256 rows][64 k]

    const int tid  = threadIdx.x;
    const int lane = tid & 63, wave = tid >> 6;
    const int wm = wave >> 2, wn = wave & 3;      // 2(M) x 4(N) waves
    const int lrow = lane & 15;

    const int wg = blockIdx.x;
    const int i  = wg >> 3;                       // 0..127 within XCD
    const int m0 = (((wg & 7) << 3) | (i >> 4)) << 8;   // xcd*8 + m_local
    const int n0 = (i & 15) << 8;

    // T2 swizzled ds_read k-offsets (u16 units)
    const int q0 = ((lane >> 4) << 3) ^ ((lrow & 7) << 3);
    const int q1 = q0 ^ 32;

    // B-expansion assignment: thread owns 32 bits = row erow, k-half ehalf
    const int erow = tid >> 1, ehalf = tid & 1;
    const u32* Wb32 = reinterpret_cast<const u32*>(Wbits);
    // bits(t) for this thread: Wb32[t*8192 + (n0+erow)*2 + ehalf] (2KB burst)

    f32x4 acc[8][4];
#pragma unroll
    for (int a = 0; a < 8; ++a)
#pragma unroll
        for (int b = 0; b < 4; ++b) acc[a][b] = (f32x4){0.f, 0.f, 0.f, 0.f};

    // stage one 128-row half of A K-tile th (2 gload_lds16 / thread)
    auto stageA = [&](int th, int half, u16* buf) {
        if (th >= NT) return;
#pragma unroll
        for (int t2 = 0; t2 < 2; ++t2) {
            const int c = half * 1024 + t2 * 512 + tid;   // 16B chunk idx
            const int row = c >> 3, c8 = c & 7;
            gload_lds16(Xbf + (size_t)(m0 + row) * IN_F + th * 64 + c8 * 8,
                        buf + c * 8);
        }
    };

    // expand 2 of this thread's 4 chunks (j = jlo, jlo+1) into Blds[dstbuf].
    // bit=1 -> +1 (0x3F80), bit=0 -> -1 (0xBF80); T2 store swizzle k8^(row&7).
    auto expandB = [&](unsigned b, int dstbuf, int jlo) {
        unsigned nb = ~b;
        u16* base = &Blds[dstbuf][erow * 64];
#pragma unroll
        for (int j = 0; j < 2; ++j) {
            const int jj = jlo + j;
            const int k8 = 4 * ehalf + jj;
            union { unsigned u[4]; u16x8 v; } r;
#pragma unroll
            for (int e = 0; e < 4; ++e) {
                unsigned s = nb >> (jj * 8 + 2 * e);
                r.u[e] = 0x3F803F80u | ((s & 1u) << 15) | ((s & 2u) << 30);
            }
            *reinterpret_cast<u16x8*>(base + ((k8 ^ (erow & 7)) << 3)) = r.v;
        }
    };

    // ---- prologue: A(0), bits(0) expanded to Blds[0], bits(1) in reg ----
    unsigned b0 = Wb32[(size_t)(n0 + erow) * 2 + ehalf];              // bits(0)
    stageA(0, 0, &Alds[0][0]); stageA(0, 1, &Alds[0][0]);
    unsigned bits_cur = Wb32[(size_t)8192 + (n0 + erow) * 2 + ehalf]; // bits(1)
    unsigned bits_nxt = 0;
    VM0();
    expandB(b0, 0, 0); expandB(b0, 0, 2);
    LGKM0(); BAR();

    for (int t = 0; t < NT; ++t) {
        const u16* Ar = &Alds[t & 1][0] + wm * 8192 + lrow * 64;
        const u16* Br = &Blds[t & 1][0] + wn * 4096 + lrow * 64;
        u16* Aw = &Alds[(t + 1) & 1][0];
        bf16x8 a0[4][2], a1[4][2], bfr[4][2];

        // --- phi0: ds_read a0 + B frags; load bits(t+2); MFMA mh0 x np0 ---
#pragma unroll
        for (int mm = 0; mm < 4; ++mm) {
            a0[mm][0] = *reinterpret_cast<const bf16x8*>(Ar + mm * 1024 + q0);
            a0[mm][1] = *reinterpret_cast<const bf16x8*>(Ar + mm * 1024 + q1);
        }
#pragma unroll
        for (int nf = 0; nf < 4; ++nf) {
            bfr[nf][0] = *reinterpret_cast<const bf16x8*>(Br + nf * 1024 + q0);
            bfr[nf][1] = *reinterpret_cast<const bf16x8*>(Br + nf * 1024 + q1);
        }
        if (t + 2 < NT)
            bits_nxt = Wb32[(size_t)(t + 2) * 8192 + (n0 + erow) * 2 + ehalf];
        BAR(); LGKM0();
        __builtin_amdgcn_s_setprio(1);
#pragma unroll
        for (int mm = 0; mm < 4; ++mm)
#pragma unroll
            for (int nn = 0; nn < 2; ++nn) {
                acc[mm][nn] = __builtin_amdgcn_mfma_f32_16x16x32_bf16(a0[mm][0], bfr[nn][0], acc[mm][nn], 0, 0, 0);
                acc[mm][nn] = __builtin_amdgcn_mfma_f32_16x16x32_bf16(a0[mm][1], bfr[nn][1], acc[mm][nn], 0, 0, 0);
            }
        __builtin_amdgcn_s_setprio(0);
        BAR();

        // --- phi1: ds_read a1; stage A(t+1) lo; MFMA mh0 x np1; expand half0 ---
#pragma unroll
        for (int mm = 0; mm < 4; ++mm) {
            a1[mm][0] = *reinterpret_cast<const bf16x8*>(Ar + (4 + mm) * 1024 + q0);
            a1[mm][1] = *reinterpret_cast<const bf16x8*>(Ar + (4 + mm) * 1024 + q1);
        }
        stageA(t + 1, 0, Aw);
        BAR();
        __builtin_amdgcn_s_setprio(1);
#pragma unroll
        for (int mm = 0; mm < 4; ++mm)
#pragma unroll
            for (int nn = 0; nn < 2; ++nn) {
                acc[mm][2 + nn] = __builtin_amdgcn_mfma_f32_16x16x32_bf16(a0[mm][0], bfr[2 + nn][0], acc[mm][2 + nn], 0, 0, 0);
                acc[mm][2 + nn] = __builtin_amdgcn_mfma_f32_16x16x32_bf16(a0[mm][1], bfr[2 + nn][1], acc[mm][2 + nn], 0, 0, 0);
            }
        __builtin_amdgcn_s_setprio(0);
        if (t + 1 < NT) expandB(bits_cur, (t + 1) & 1, 0);  // under matrix pipe
        BAR();

        // --- phi2: stage A(t+1) hi; drain a1; MFMA mh1 x np0; expand half1 ---
        stageA(t + 1, 1, Aw);
        BAR(); LGKM0();
        __builtin_amdgcn_s_setprio(1);
#pragma unroll
        for (int mm = 0; mm < 4; ++mm)
#pragma unroll
            for (int nn = 0; nn < 2; ++nn) {
                acc[4 + mm][nn] = __builtin_amdgcn_mfma_f32_16x16x32_bf16(a1[mm][0], bfr[nn][0], acc[4 + mm][nn], 0, 0, 0);
                acc[4 + mm][nn] = __builtin_amdgcn_mfma_f32_16x16x32_bf16(a1[mm][1], bfr[nn][1], acc[4 + mm][nn], 0, 0, 0);
            }
        __builtin_amdgcn_s_setprio(0);
        if (t + 1 < NT) expandB(bits_cur, (t + 1) & 1, 2);
        BAR();

        // --- phi3: MFMA mh1 x np1; boundary: writes visible + loads drained ---
        __builtin_amdgcn_s_setprio(1);
#pragma unroll
        for (int mm = 0; mm < 4; ++mm)
#pragma unroll
            for (int nn = 0; nn < 2; ++nn) {
                acc[4 + mm][2 + nn] = __builtin_amdgcn_mfma_f32_16x16x32_bf16(a1[mm][0], bfr[2 + nn][0], acc[4 + mm][2 + nn], 0, 0, 0);
                acc[4 + mm][2 + nn] = __builtin_amdgcn_mfma_f32_16x16x32_bf16(a1[mm][1], bfr[2 + nn][1], acc[4 + mm][2 + nn], 0, 0, 0);
            }
        __builtin_amdgcn_s_setprio(0);
        LGKM0(); VM0(); BAR();

        bits_cur = bits_nxt;
    }

    // epilogue: y = acc*alpha[col] + bias[col]; C/D: col=lane&15, row=(lane>>4)*4+r
#pragma unroll
    for (int nf = 0; nf < 4; ++nf) {
        const int col = n0 + wn * 64 + nf * 16 + lrow;
        const float al = alpha[col], bi = bias[col];
#pragma unroll
        for (int mf = 0; mf < 8; ++mf) {
            const int rbase = m0 + wm * 128 + mf * 16 + ((lane >> 4) << 2);
#pragma unroll
            for (int r = 0; r < 4; ++r)
                __builtin_nontemporal_store(acc[mf][nf][r] * al + bi,
                    &Y[(size_t)(rbase + r) * OUT_F + col]);
        }
    }
}

// ============================================================================
// Fallback (small workspace): round-1 128x128 kernel, A reg-staged from fp32,
// bf16 Wsign unswizzled. Verified correct in round 1.
// ============================================================================
__global__ void prep_w_kernel(const float* __restrict__ W,
                              float* __restrict__ alpha,
                              u16* __restrict__ S) {
    const int row = blockIdx.x;
    const float* wr = W + (size_t)row * IN_F;
    float s = 0.f;
    for (int c = threadIdx.x; c < 512; c += 256) {
        const f32x4* src = reinterpret_cast<const f32x4*>(wr + c * 8);
        f32x4 v0 = __builtin_nontemporal_load(src);
        f32x4 v1 = __builtin_nontemporal_load(src + 1);
        s += fabsf(v0[0]) + fabsf(v0[1]) + fabsf(v0[2]) + fabsf(v0[3])
           + fabsf(v1[0]) + fabsf(v1[1]) + fabsf(v1[2]) + fabsf(v1[3]);
        u16x8 r;
        r[0] = sgn_bf16(v0[0]); r[1] = sgn_bf16(v0[1]);
        r[2] = sgn_bf16(v0[2]); r[3] = sgn_bf16(v0[3]);
        r[4] = sgn_bf16(v1[0]); r[5] = sgn_bf16(v1[1]);
        r[6] = sgn_bf16(v1[2]); r[7] = sgn_bf16(v1[3]);
        *reinterpret_cast<u16x8*>(S + (size_t)row * IN_F + c * 8) = r;
    }
    for (int off = 32; off > 0; off >>= 1) s += __shfl_down(s, off);
    __shared__ float red[4];
    const int wave = threadIdx.x >> 6, lane = threadIdx.x & 63;
    if (lane == 0) red[wave] = s;
    __syncthreads();
    if (threadIdx.x == 0)
        alpha[row] = (red[0] + red[1] + red[2] + red[3]) * (1.0f / IN_F);
}

__global__ __launch_bounds__(256) void gemm_fallback(
    const float* __restrict__ X, const u16* __restrict__ Wsign,
    const float* __restrict__ alpha, const float* __restrict__ bias,
    float* __restrict__ Y) {
    __shared__ u16 Axl[128 * 64];
    __shared__ u16 Bxl[128 * 64];

    const int tid = threadIdx.x;
    const int n0 = blockIdx.x * 128;
    const int m0 = blockIdx.y * 128;
    const int wave = tid >> 6, lane = tid & 63;
    const int wm = wave >> 1, wn = wave & 1;
    const int lrow = lane & 15;
    const int lk8 = (lane >> 4) * 8;

    f32x4 acc[4][4];
#pragma unroll
    for (int a = 0; a < 4; ++a)
#pragma unroll
        for (int b = 0; b < 4; ++b) acc[a][b] = (f32x4){0.f, 0.f, 0.f, 0.f};

    for (int kt = 0; kt < IN_F; kt += 64) {
#pragma unroll
        for (int j = 0; j < 4; ++j) {
            const int idx = j * 256 + tid;
            const int row = idx >> 3, c8 = idx & 7;
            gload_lds16(Wsign + (size_t)(n0 + row) * IN_F + kt + c8 * 8,
                        &Bxl[idx * 8]);
        }
#pragma unroll
        for (int j = 0; j < 4; ++j) {
            const int idx = j * 256 + tid;
            const int row = idx >> 3, c8 = idx & 7;
            const float* src = X + (size_t)(m0 + row) * IN_F + kt + c8 * 8;
            float4 v0 = *reinterpret_cast<const float4*>(src);
            float4 v1 = *reinterpret_cast<const float4*>(src + 4);
            u16x8 r;
            r[0] = f2bf(v0.x); r[1] = f2bf(v0.y); r[2] = f2bf(v0.z); r[3] = f2bf(v0.w);
            r[4] = f2bf(v1.x); r[5] = f2bf(v1.y); r[6] = f2bf(v1.z); r[7] = f2bf(v1.w);
            *reinterpret_cast<u16x8*>(&Axl[idx * 8]) = r;
        }
        __syncthreads();
#pragma unroll
        for (int kk = 0; kk < 2; ++kk) {
            bf16x8 af[4], bfv[4];
#pragma unroll
            for (int mf = 0; mf < 4; ++mf)
                af[mf] = *reinterpret_cast<const bf16x8*>(
                    &Axl[(wm * 64 + mf * 16 + lrow) * 64 + kk * 32 + lk8]);
#pragma unroll
            for (int nf = 0; nf < 4; ++nf)
                bfv[nf] = *reinterpret_cast<const bf16x8*>(
                    &Bxl[(wn * 64 + nf * 16 + lrow) * 64 + kk * 32 + lk8]);
#pragma unroll
            for (int mf = 0; mf < 4; ++mf)
#pragma unroll
                for (int nf = 0; nf < 4; ++nf)
                    acc[mf][nf] = __builtin_amdgcn_mfma_f32_16x16x32_bf16(
                        af[mf], bfv[nf], acc[mf][nf], 0, 0, 0);
        }
        __syncthreads();
    }
#pragma unroll
    for (int nf = 0; nf < 4; ++nf) {
        const int col = n0 + wn * 64 + nf * 16 + lrow;
        const float al = alpha[col], bi = bias[col];
#pragma unroll
        for (int mf = 0; mf < 4; ++mf) {
            const int rbase = m0 + wm * 64 + mf * 16 + (lane >> 4) * 4;
#pragma unroll
            for (int r = 0; r < 4; ++r)
                __builtin_nontemporal_store(acc[mf][nf][r] * al + bi,
                    &Y[(size_t)(rbase + r) * OUT_F + col]);
        }
    }
}

extern "C" void kernel_launch(void* const* d_in, const int* in_sizes, int n_in,
                              void* d_out, int out_size, void* d_ws, size_t ws_size,
                              hipStream_t stream) {
    const float* X    = (const float*)d_in[0];
    const float* W    = (const float*)d_in[1];
    const float* bias = (const float*)d_in[2];
    float* Y = (float*)d_out;

    char* ws = (char*)d_ws;
    float* alpha = (float*)ws;                               // 16 KB
    const size_t WBITS_OFF = 16384;
    const size_t XBF_OFF   = WBITS_OFF + (size_t)OUT_F * (IN_F / 8); // +2 MB
    const size_t need_fast = XBF_OFF + (size_t)NROWS * IN_F * 2;     // +128 MB
    const size_t need_safe = 16384 + (size_t)OUT_F * IN_F * 2;       // 32 MB path

    if (ws_size >= need_fast) {
        u64* Wbits = (u64*)(ws + WBITS_OFF);
        u16* Xbf   = (u16*)(ws + XBF_OFF);
        prep_wbits_kernel<<<OUT_F, 256, 0, stream>>>(W, alpha, Wbits);
        convx_kernel<<<(size_t)NROWS * IN_F / 8 / 256, 256, 0, stream>>>(X, Xbf, 1);
        gemm8_kernel<<<dim3(1024), 512, 0, stream>>>(Xbf, Wbits, alpha, bias, Y);
    } else {
        u16* Wsign = (u16*)(ws + 16384);
        prep_w_kernel<<<OUT_F, 256, 0, stream>>>(W, alpha, Wsign);
        dim3 grid(OUT_F / 128, NROWS / 128);
        gemm_fallback<<<grid, 256, 0, stream>>>(X, Wsign, alpha, bias, Y);
    }
}